// Round 6
// baseline (31.075 us; speedup 1.0000x reference)
//
#include <hip/hip_runtime.h>
#include <stdint.h>

#define SEQ   8192
#define NB    128
#define MAXP  4096
#define TOT4  (NB * SEQ / 4)      // int4 groups in tokens buffer

// ---- ws layout (u32 units) ----
#define WS_SIZES  0               // 128 seq * 2048 u32  (sizes8, byte per pos)
#define WS_EXITF  262144          // 128 seq * 1024 u32  (256 chunks * 16B exit fn)
#define WS_CNTF   393216          // 128 seq * 1024 u32  (256 chunks * 16B cnt fn)
#define WS_ENTRY  524288          // 128 seq * 64 u32    (256 entry bytes)
#define WS_PBASE  532480          // 128 seq * 130 u32   (257 u16 patch bases, [256]=P)
#define WS_TOTAL  549120
#define WS_NEEDED ((size_t)WS_TOTAL * 4)

__device__ __forceinline__ bool haszero8(uint64_t v) {
    return ((v - 0x0101010101010101ULL) & ~v & 0x8080808080808080ULL) != 0ULL;
}
__device__ __forceinline__ bool distinct8(uint64_t w) {
    uint64_t r1 = (w >> 8)  | (w << 56);
    uint64_t r2 = (w >> 16) | (w << 48);
    uint64_t r3 = (w >> 24) | (w << 40);
    uint64_t r4 = (w >> 32) | (w << 32);
    return !(haszero8(w ^ r1) | haszero8(w ^ r2) | haszero8(w ^ r3) | haszero8(w ^ r4));
}
__device__ __forceinline__ uint32_t pack4(int4 v) {
    return (uint32_t)(v.x & 255) | ((uint32_t)(v.y & 255) << 8) |
           ((uint32_t)(v.z & 255) << 16) | ((uint32_t)(v.w & 255) << 24);
}
__device__ __forceinline__ uint32_t bsel16(uint4 f, uint32_t b) {
    uint32_t w01 = (b & 4u) ? f.y : f.x;
    uint32_t w23 = (b & 4u) ? f.w : f.z;
    uint32_t w   = (b & 8u) ? w23 : w01;
    return (w >> ((b & 3u) << 3)) & 255u;
}
// r.byte[i] = g.byte[f.byte[i]]  (values in [0,16)) -- proven in round 5
__device__ __forceinline__ uint4 comp16(uint4 g, uint4 f) {
    uint4 r;
#if __has_builtin(__builtin_amdgcn_perm)
    #define C16W(fw, out) do { \
        uint32_t sel = (fw) & 0x07070707u; \
        uint32_t lo = __builtin_amdgcn_perm(g.y, g.x, sel); \
        uint32_t hi = __builtin_amdgcn_perm(g.w, g.z, sel); \
        uint32_t m = ((fw) & 0x08080808u) >> 3; m = (m << 8) - m; \
        out = (lo & ~m) | (hi & m); } while (0)
    C16W(f.x, r.x); C16W(f.y, r.y); C16W(f.z, r.z); C16W(f.w, r.w);
    #undef C16W
#else
    #define C16B(fw, out) do { uint32_t o = 0; \
        o |= bsel16(g, (fw) & 15u); \
        o |= bsel16(g, ((fw) >> 8) & 15u) << 8; \
        o |= bsel16(g, ((fw) >> 16) & 15u) << 16; \
        o |= bsel16(g, ((fw) >> 24) & 15u) << 24; \
        out = o; } while (0)
    C16B(f.x, r.x); C16B(f.y, r.y); C16B(f.z, r.z); C16B(f.w, r.w);
    #undef C16B
#endif
    return r;
}

// ---------- K1: quarter-sequence prep: stop bits, sizes, chunk transfer fns -------
__global__ __launch_bounds__(256) void ep_prep(const int* __restrict__ tokens,
                                               uint32_t* __restrict__ ws) {
    __shared__ uint32_t tok32[520];     // 2048 tokens + 32 halo (u8-packed)
    __shared__ uint8_t  stop8[264];     // 258 window-group bytes + zero pad
    __shared__ uint32_t stopb[66];      // 65 words + zero pad
    __shared__ uint8_t  sizes8s[2048];

    const int bq = blockIdx.x;
    const int b = bq >> 2, q = bq & 3;
    const int tid = threadIdx.x;
    const int4* t4 = (const int4*)tokens;
    const int gbase = b * 2048 + q * 512;        // int4 group base of this quarter

    // stage quarter + halo
    tok32[tid]       = pack4(t4[gbase + tid]);
    tok32[256 + tid] = pack4(t4[gbase + 256 + tid]);
    if (tid < 8) {
        int g4 = gbase + 512 + tid;
        tok32[512 + tid] = (g4 < TOT4) ? pack4(t4[g4]) : 0u;
    }
    if (tid >= 2 && tid < 8) stop8[256 + tid] = 0;   // pad groups 258..263
    if (tid == 0) stopb[65] = 0;
    __syncthreads();

    // stop bits: 258 groups of 8 windows (2048 quarter + 16 halo)
    for (int g = tid; g < 258; g += 256) {
        const int wb = g * 2;
        uint64_t win = (uint64_t)tok32[wb] | ((uint64_t)tok32[wb + 1] << 32);
        uint32_t byte = 0;
        #pragma unroll
        for (int k = 0; k < 2; ++k) {
            uint32_t nx = tok32[wb + 2 + k];
            #pragma unroll
            for (int m = 0; m < 4; ++m) {
                int jg = q * 2048 + g * 8 + k * 4 + m;
                if (jg <= SEQ - 8 && distinct8(win)) byte |= 1u << (k * 4 + m);
                win = (win >> 8) | ((uint64_t)(nx & 255u) << 56);
                nx >>= 8;
            }
        }
        stop8[g] = (uint8_t)byte;
    }
    __syncthreads();
    if (tid < 65)
        stopb[tid] = (uint32_t)stop8[4 * tid] | ((uint32_t)stop8[4 * tid + 1] << 8)
                   | ((uint32_t)stop8[4 * tid + 2] << 16) | ((uint32_t)stop8[4 * tid + 3] << 24);
    __syncthreads();

    // sizes (proven formula), keep in LDS + write to ws
    {
        #pragma unroll
        for (int w = 0; w < 2; ++w) {
            uint32_t acc = 0;
            #pragma unroll
            for (int m = 0; m < 4; ++m) {
                int il = tid * 8 + w * 4 + m;
                int bp = il + 2, ww = bp >> 5;
                uint64_t comb = (uint64_t)stopb[ww] | ((uint64_t)stopb[ww + 1] << 32);
                uint32_t win14 = (uint32_t)(comb >> (bp & 31)) & 0x3FFFu;
                int ig = q * 2048 + il;
                int sz = win14 ? (2 + __builtin_ctz(win14)) : min(16, SEQ - ig);
                acc |= (uint32_t)sz << (m * 8);
            }
            ((uint32_t*)sizes8s)[tid * 2 + w] = acc;
            ws[WS_SIZES + b * 2048 + q * 512 + tid * 2 + w] = acc;
        }
    }
    __syncthreads();

    // chunk transfer functions: 64 chunks of 32, 4 threads/chunk, 4 entries each
    {
        const int ch = tid >> 2, sub = tid & 3;
        const int cb = ch * 32;
        int pp[4], cc[4];
        #pragma unroll
        for (int k = 0; k < 4; ++k) { pp[k] = cb + sub * 4 + k; cc[k] = 0; }
        for (int it = 0; it < 17; ++it) {
            #pragma unroll
            for (int k = 0; k < 4; ++k) {
                bool a = pp[k] < cb + 32;
                int s = (int)sizes8s[a ? pp[k] : cb];
                if (a) { cc[k]++; pp[k] += s; }
            }
        }
        uint32_t xw = 0, cw = 0;
        #pragma unroll
        for (int k = 0; k < 4; ++k) {
            xw |= (uint32_t)(pp[k] - (cb + 32)) << (k * 8);
            cw |= (uint32_t)cc[k] << (k * 8);
        }
        const int fidx = b * 1024 + (q * 64 + ch) * 4 + sub;
        ws[WS_EXITF + fidx] = xw;
        ws[WS_CNTF  + fidx] = cw;
    }
}

// ---------- K2: per-sequence function scan -> entries + patch bases ----------------
__global__ __launch_bounds__(64) void ep_scan(uint32_t* __restrict__ ws) {
    const int b = blockIdx.x, t = threadIdx.x;
    const uint4* xf = (const uint4*)(ws + WS_EXITF + b * 1024);
    uint4 f0 = xf[4 * t], f1 = xf[4 * t + 1], f2 = xf[4 * t + 2], f3 = xf[4 * t + 3];
    uint4 g = comp16(f1, f0);
    g = comp16(f2, g);
    g = comp16(f3, g);
    #pragma unroll
    for (int d = 1; d < 64; d <<= 1) {
        uint4 o;
        o.x = (uint32_t)__shfl_up((int)g.x, d);
        o.y = (uint32_t)__shfl_up((int)g.y, d);
        o.z = (uint32_t)__shfl_up((int)g.z, d);
        o.w = (uint32_t)__shfl_up((int)g.w, d);
        if (t >= d) g = comp16(g, o);
    }
    uint4 E;
    E.x = (uint32_t)__shfl_up((int)g.x, 1);
    E.y = (uint32_t)__shfl_up((int)g.y, 1);
    E.z = (uint32_t)__shfl_up((int)g.z, 1);
    E.w = (uint32_t)__shfl_up((int)g.w, 1);
    if (t == 0) E = make_uint4(0x03020100u, 0x07060504u, 0x0B0A0908u, 0x0F0E0D0Cu);
    uint32_t e0 = E.x & 255u;
    uint32_t e1 = bsel16(f0, e0);
    uint32_t e2 = bsel16(f1, e1);
    uint32_t e3 = bsel16(f2, e2);
    const uint8_t* cf = (const uint8_t*)(ws + WS_CNTF + b * 1024);
    int c0 = cf[(4 * t) * 16 + e0],     c1 = cf[(4 * t + 1) * 16 + e1];
    int c2 = cf[(4 * t + 2) * 16 + e2], c3 = cf[(4 * t + 3) * 16 + e3];
    int s = c0 + c1 + c2 + c3;
    int incl = s;
    #pragma unroll
    for (int d = 1; d < 64; d <<= 1) { int o = __shfl_up(incl, d); if (t >= d) incl += o; }
    int excl = incl - s;
    ws[WS_ENTRY + b * 64 + t] = e0 | (e1 << 8) | (e2 << 16) | (e3 << 24);
    uint32_t* pbw = ws + WS_PBASE + b * 130;
    pbw[2 * t]     = (uint32_t)(excl & 0xFFFF) | ((uint32_t)(excl + c0) << 16);
    pbw[2 * t + 1] = (uint32_t)((excl + c0 + c1) & 0xFFFF)
                   | ((uint32_t)(excl + c0 + c1 + c2) << 16);
    if (t == 63) pbw[128] = (uint32_t)incl;       // pbase[256] = total P
}

// ---------- K3: self-sufficient emission, 16 blocks/seq ----------------------------
__global__ __launch_bounds__(256) void ep_emit(const int* __restrict__ tokens,
                                               const uint32_t* __restrict__ ws,
                                               int* __restrict__ out) {
    __shared__ uint32_t tokw[136];      // 544 tokens (512 span + halo)
    __shared__ uint8_t  sz_l[512];
    __shared__ uint16_t lstarts[520];
    __shared__ uint8_t  ent_l[20];
    __shared__ uint16_t pbs_l[20];
    __shared__ int      nloc_s, P_ss;

    const int bx = blockIdx.x;
    const int b = bx >> 4, c = bx & 15, tid = threadIdx.x;

    if (tid < 136) {
        int g4 = b * 2048 + c * 128 + tid;
        tokw[tid] = (g4 < TOT4) ? pack4(((const int4*)tokens)[g4]) : 0u;
    }
    if (tid < 128) ((uint32_t*)sz_l)[tid] = ws[WS_SIZES + b * 2048 + c * 128 + tid];
    if (tid < 17) {
        const uint8_t* en = (const uint8_t*)(ws + WS_ENTRY + b * 64);
        ent_l[tid] = (c * 16 + tid < 256) ? en[c * 16 + tid] : (uint8_t)0;
        const uint16_t* pb = (const uint16_t*)(ws + WS_PBASE + b * 130);
        pbs_l[tid] = pb[c * 16 + tid];              // c=15,tid=16 -> pb[256]=P (valid)
    }
    if (tid == 17) P_ss = (int)((const uint16_t*)(ws + WS_PBASE + b * 130))[256];
    __syncthreads();

    // expand 16 chunks in parallel (walk stays inside chunk by construction)
    if (tid < 16) {
        int p = tid * 32 + (int)ent_l[tid];
        const int lim = tid * 32 + 32;
        int pb = (int)pbs_l[tid] - (int)pbs_l[0];
        while (p < lim) { lstarts[pb++] = (uint16_t)p; p += (int)sz_l[p]; }
    }
    if (tid == 16) {
        int nl = (int)pbs_l[16] - (int)pbs_l[0];
        nloc_s = nl;
        lstarts[nl] = (uint16_t)(512 + ((c < 15) ? (int)ent_l[16] : 0));  // next start
    }
    __syncthreads();

    const int nloc = nloc_s, pb0 = (int)pbs_l[0], P = P_ss;
    const uint8_t* tok8 = (const uint8_t*)tokw;
    int* outp = out + (size_t)b * (MAXP * 16);
    int* outm = out + (size_t)NB * MAXP * 16 + (size_t)b * MAXP;
    const int qq = tid & 3;
    #pragma unroll
    for (int it = 0; it < 8; ++it) {
        int p = it * 64 + (tid >> 2);
        if (p < nloc) {
            int st  = (int)lstarts[p];
            int szp = (int)lstarts[p + 1] - st;
            int off = st + qq * 4;
            int t0[4];
            #pragma unroll
            for (int j = 0; j < 4; ++j) {
                int l = qq * 4 + j;
                int idx = off + j; if (idx > 543) idx = 543;
                t0[j] = (l < szp) ? (int)tok8[idx] : 0;
            }
            ((int4*)outp)[(size_t)(pb0 + p) * 4 + qq] = make_int4(t0[0], t0[1], t0[2], t0[3]);
        }
    }
    for (int pm = tid; pm < nloc; pm += 256) outm[pb0 + pm] = 1;
    {
        int idx = c * 256 + tid;                    // static share tiles [0,4096)
        if (idx >= P) {
            int4 z = make_int4(0, 0, 0, 0);
            int4* d = (int4*)(outp + (size_t)idx * 16);
            d[0] = z; d[1] = z; d[2] = z; d[3] = z;
            outm[idx] = 0;
        }
    }
}

// ---------- Fallback (ws too small): proven round-1 monolithic ---------------------
__global__ __launch_bounds__(256) void ep_mono(const int* __restrict__ tokens,
                                               int* __restrict__ out) {
    __shared__ uint32_t tok32[2052];
    __shared__ uint32_t stopb[258];
    __shared__ uint8_t  sizes_s[SEQ];
    __shared__ uint16_t f_s[SEQ];
    __shared__ uint16_t starts_s[MAXP + 4];
    __shared__ int      entry_s[130];
    __shared__ int      base_s[130];
    __shared__ int      P_s, nv_s;

    const int b = blockIdx.x, tid = threadIdx.x;
    const int* tseq = tokens + (size_t)b * SEQ;
    {
        const int4* t4 = (const int4*)tseq;
        #pragma unroll
        for (int k = 0; k < 8; ++k) { int g = k * 256 + tid; tok32[g] = pack4(t4[g]); }
        if (tid < 4) tok32[2048 + tid] = 0u;
        if (tid < 2) stopb[256 + tid] = 0u;
    }
    __syncthreads();
    {
        const int base = tid * 8;
        uint64_t win = (uint64_t)tok32[base] | ((uint64_t)tok32[base + 1] << 32);
        uint32_t bits = 0;
        #pragma unroll
        for (int k = 0; k < 8; ++k) {
            uint32_t nx = tok32[base + 2 + k];
            #pragma unroll
            for (int m = 0; m < 4; ++m) {
                int j = tid * 32 + k * 4 + m;
                if (j <= SEQ - 8 && distinct8(win)) bits |= (1u << (k * 4 + m));
                win = (win >> 8) | ((uint64_t)(nx & 255u) << 56);
                nx >>= 8;
            }
        }
        stopb[tid] = bits;
    }
    __syncthreads();
    {
        const int i0 = tid * 32;
        #pragma unroll 4
        for (int m = 0; m < 32; ++m) {
            int i = i0 + m, bp = i + 2, w = bp >> 5;
            uint64_t comb = (uint64_t)stopb[w] | ((uint64_t)stopb[w + 1] << 32);
            uint32_t win14 = (uint32_t)(comb >> (bp & 31)) & 0x3FFFu;
            int sz = win14 ? (2 + __builtin_ctz(win14)) : min(16, SEQ - i);
            sizes_s[i] = (uint8_t)sz;
        }
    }
    __syncthreads();
    if (tid < 128) {
        const int cbase = tid * 64, cend = cbase + 64;
        for (int i = cend - 1; i >= cbase; --i) {
            int j = i + (int)sizes_s[i];
            uint16_t fv;
            if (j >= cend) fv = (uint16_t)((j - cbase) | (1u << 8));
            else { uint16_t fj = f_s[j];
                   fv = (uint16_t)((fj & 255u) | ((uint32_t)((fj >> 8) + 1u) << 8)); }
            f_s[i] = fv;
        }
    }
    __syncthreads();
    if (tid == 0) {
        int i = 0, pidx = 0, m = 0;
        while (i < SEQ) {
            entry_s[m] = i; base_s[m] = pidx;
            uint16_t fv = f_s[i];
            pidx += (int)(fv >> 8);
            i = (i & ~63) + (int)(fv & 255u);
            ++m;
        }
        P_s = pidx; nv_s = m;
        starts_s[pidx] = (uint16_t)SEQ;
    }
    __syncthreads();
    if (tid < nv_s) {
        int i = entry_s[tid], p = base_s[tid];
        const int cend = (i & ~63) + 64;
        while (i < cend) { starts_s[p++] = (uint16_t)i; i += (int)sizes_s[i]; }
    }
    __syncthreads();
    const int P = P_s;
    int* outp = out + (size_t)b * MAXP * 16;
    int* outm = out + (size_t)NB * MAXP * 16 + (size_t)b * MAXP;
    const uint8_t* tok8 = (const uint8_t*)tok32;
    for (int p = tid; p < MAXP; p += 256) {
        int4 o0 = make_int4(0,0,0,0), o1 = o0, o2 = o0, o3 = o0;
        int msk = 0;
        if (p < P) {
            msk = 1;
            int st = (int)starts_s[p];
            int sz = (int)starts_s[p + 1] - st;
            int t[16];
            #pragma unroll
            for (int l = 0; l < 16; ++l) t[l] = (l < sz) ? (int)tok8[st + l] : 0;
            o0 = make_int4(t[0],t[1],t[2],t[3]);   o1 = make_int4(t[4],t[5],t[6],t[7]);
            o2 = make_int4(t[8],t[9],t[10],t[11]); o3 = make_int4(t[12],t[13],t[14],t[15]);
        }
        int4* dst = (int4*)(outp + (size_t)p * 16);
        dst[0] = o0; dst[1] = o1; dst[2] = o2; dst[3] = o3;
        outm[p] = msk;
    }
}

extern "C" void kernel_launch(void* const* d_in, const int* in_sizes, int n_in,
                              void* d_out, int out_size, void* d_ws, size_t ws_size,
                              hipStream_t stream) {
    const int* tokens = (const int*)d_in[0];
    int* out = (int*)d_out;
    if (ws_size >= WS_NEEDED) {
        uint32_t* ws = (uint32_t*)d_ws;
        ep_prep<<<dim3(NB * 4), dim3(256), 0, stream>>>(tokens, ws);
        ep_scan<<<dim3(NB), dim3(64), 0, stream>>>(ws);
        ep_emit<<<dim3(NB * 16), dim3(256), 0, stream>>>(tokens, ws, out);
    } else {
        ep_mono<<<dim3(NB), dim3(256), 0, stream>>>(tokens, out);
    }
}